// Round 1
// baseline (405.252 us; speedup 1.0000x reference)
//
#include <hip/hip_runtime.h>
#include <hip/hip_bf16.h>

typedef unsigned long long u64;

#define IMG_H 256
#define IMG_W 256
#define CIN   64
#define HW    (IMG_H * IMG_W)   // 65536

// ---------------------------------------------------------------------------
// Kernel P: pack weight sign bits + per-out-channel alpha = mean(|w|).
// One wave (64 lanes) per output channel; lane i <-> input channel i.
// blocks 0..63 -> w1 (64 out ch), blocks 64..191 -> w2 (128 out ch).
// ---------------------------------------------------------------------------
__global__ void prep_kernel(const float* __restrict__ w1,
                            const float* __restrict__ w2,
                            u64* __restrict__ w1b, float* __restrict__ a1,
                            u64* __restrict__ w2b, float* __restrict__ a2) {
    int blk = blockIdx.x;
    int lane = threadIdx.x;  // 0..63
    const float* w;
    u64* wb;
    float* al;
    if (blk < 64) { w = w1 + (size_t)blk * 576;        wb = w1b + blk * 9;        al = a1 + blk; }
    else          { w = w2 + (size_t)(blk - 64) * 576; wb = w2b + (blk - 64) * 9; al = a2 + (blk - 64); }

    const float* wi = w + lane * 9;   // [i][t]
    float s = 0.f;
    u64 bits[9];
#pragma unroll
    for (int t = 0; t < 9; ++t) {
        float v = wi[t];
        s += fabsf(v);
        bits[t] = __ballot(v > 0.f);   // bit i = sign(+) of input channel i
    }
#pragma unroll
    for (int m = 32; m >= 1; m >>= 1) s += __shfl_xor(s, m);
    if (lane == 0) {
        *al = s * (1.f / 576.f);
#pragma unroll
        for (int t = 0; t < 9; ++t) wb[t] = bits[t];
    }
}

// ---------------------------------------------------------------------------
// Kernel A: conv1 (binary popcount) + residual. Per 32x32 tile:
//   phase 1: pack sign(x + b_in) bits for tile+1 halo into LDS (u64/pixel)
//   phase 2: per pixel, per out channel o: S = 64*nv - 2*popc-mismatch;
//            xres = alpha1[o]*S + x   -> store bf16
//            bit o of bits2 = (xres + b2_[o]) > 0 -> store u64 bit-plane
// ---------------------------------------------------------------------------
__global__ __launch_bounds__(256)
void convbin1_kernel(const float* __restrict__ x,
                     const float* __restrict__ b_in,
                     const float* __restrict__ b2_,
                     const u64* __restrict__ wbits,
                     const float* __restrict__ alpha1,
                     __hip_bfloat16* __restrict__ xres,
                     u64* __restrict__ bits2) {
    __shared__ u64 lb[34 * 34];
    const int n = blockIdx.z;
    const int ty0 = blockIdx.y * 32;
    const int tx0 = blockIdx.x * 32;
    const float* xn = x + (size_t)n * CIN * HW;

    // phase 1: pack activation sign bits (0 for out-of-image; validity handled later)
    for (int idx = threadIdx.x; idx < 34 * 34; idx += 256) {
        int ly = idx / 34, lx = idx % 34;
        int gy = ty0 + ly - 1, gx = tx0 + lx - 1;
        u64 wrd = 0;
        if (gy >= 0 && gy < IMG_H && gx >= 0 && gx < IMG_W) {
            const float* p = xn + gy * IMG_W + gx;
#pragma unroll 8
            for (int c = 0; c < 64; ++c) {
                float v = p[(size_t)c * HW] + b_in[c];
                wrd |= (u64)(v > 0.f) << c;
            }
        }
        lb[idx] = wrd;
    }
    __syncthreads();

    const int lx = threadIdx.x & 31;
    const int ry = threadIdx.x >> 5;  // 0..7

    for (int py = ry; py < 32; py += 8) {
        const int gy = ty0 + py;
        const int gx = tx0 + lx;

        u64 xb9[9];
        int invmask = 0, nv = 0;
#pragma unroll
        for (int t = 0; t < 9; ++t) {
            int dy = t / 3 - 1, dx = t % 3 - 1;
            int yy = gy + dy, xx = gx + dx;
            bool valid = (yy >= 0) & (yy < IMG_H) & (xx >= 0) & (xx < IMG_W);
            xb9[t] = lb[(py + 1 + dy) * 34 + (lx + 1 + dx)];  // already 0 if invalid
            invmask |= (valid ? 0 : 1) << t;
            nv += valid ? 1 : 0;
        }

        const float* xp = xn + gy * IMG_W + gx;
        __hip_bfloat16* rp = xres + (size_t)n * CIN * HW + gy * IMG_W + gx;
        u64 w2word = 0;

        for (int o = 0; o < 64; ++o) {
            const u64* wo = wbits + o * 9;
            int D = 0;
#pragma unroll
            for (int t = 0; t < 9; ++t) D += __popcll(xb9[t] ^ wo[t]);
            if (invmask) {
#pragma unroll
                for (int t = 0; t < 9; ++t)
                    if ((invmask >> t) & 1) D -= __popcll(wo[t]);
            }
            int S = 64 * nv - 2 * D;
            float r = alpha1[o] * (float)S + xp[(size_t)o * HW];
            rp[(size_t)o * HW] = __float2bfloat16(r);
            w2word |= (u64)((r + b2_[o]) > 0.f) << o;
        }
        bits2[(size_t)n * HW + gy * IMG_W + gx] = w2word;
    }
}

// ---------------------------------------------------------------------------
// Kernel B: conv2 (binary popcount) + shortcut cat(xres,xres) + b3 + PReLU(s2)
//           + b4 + pixel_shuffle(2) fused into the store.
// out[n, co, 2y+r1, 2x+r2] = v(o = co*4 + r1*2 + r2)
// Channels (o, o+1) for even o share (co, r1) -> float2 coalesced store.
// ---------------------------------------------------------------------------
__global__ __launch_bounds__(256)
void convbin2_kernel(const __hip_bfloat16* __restrict__ xres,
                     const u64* __restrict__ bits2,
                     const u64* __restrict__ wbits,
                     const float* __restrict__ alpha2,
                     const float* __restrict__ b3,
                     const float* __restrict__ s2,
                     const float* __restrict__ b4,
                     float* __restrict__ out) {
    __shared__ u64 lb[34 * 34];
    const int n = blockIdx.z;
    const int ty0 = blockIdx.y * 32;
    const int tx0 = blockIdx.x * 32;
    const u64* bn = bits2 + (size_t)n * HW;

    for (int idx = threadIdx.x; idx < 34 * 34; idx += 256) {
        int ly = idx / 34, lx = idx % 34;
        int gy = ty0 + ly - 1, gx = tx0 + lx - 1;
        u64 wrd = 0;
        if (gy >= 0 && gy < IMG_H && gx >= 0 && gx < IMG_W)
            wrd = bn[gy * IMG_W + gx];
        lb[idx] = wrd;
    }
    __syncthreads();

    const int lx = threadIdx.x & 31;
    const int ry = threadIdx.x >> 5;

    for (int py = ry; py < 32; py += 8) {
        const int gy = ty0 + py;
        const int gx = tx0 + lx;

        u64 xb9[9];
        int invmask = 0, nv = 0;
#pragma unroll
        for (int t = 0; t < 9; ++t) {
            int dy = t / 3 - 1, dx = t % 3 - 1;
            int yy = gy + dy, xx = gx + dx;
            bool valid = (yy >= 0) & (yy < IMG_H) & (xx >= 0) & (xx < IMG_W);
            xb9[t] = lb[(py + 1 + dy) * 34 + (lx + 1 + dx)];
            invmask |= (valid ? 0 : 1) << t;
            nv += valid ? 1 : 0;
        }

        const __hip_bfloat16* rp = xres + (size_t)n * CIN * HW + gy * IMG_W + gx;
        // output base for this pixel (pre-shuffle spatial (gy,gx))
        float* ob = out + (size_t)n * 32 * 512 * 512;

        for (int cp = 0; cp < 64; cp += 2) {
            float xr0 = __bfloat162float(rp[(size_t)cp * HW]);
            float xr1 = __bfloat162float(rp[(size_t)(cp + 1) * HW]);
            float v[4];
#pragma unroll
            for (int j = 0; j < 4; ++j) {
                int o = (j < 2) ? (cp + j) : (cp + 62 + j);  // cp, cp+1, cp+64, cp+65
                const u64* wo = wbits + o * 9;
                int D = 0;
#pragma unroll
                for (int t = 0; t < 9; ++t) D += __popcll(xb9[t] ^ wo[t]);
                if (invmask) {
#pragma unroll
                    for (int t = 0; t < 9; ++t)
                        if ((invmask >> t) & 1) D -= __popcll(wo[t]);
                }
                int S = 64 * nv - 2 * D;
                float u = 1.25f * alpha2[o] * (float)S + ((j & 1) ? xr1 : xr0) + b3[o];
                u = (u >= 0.f) ? u : s2[o] * u;
                v[j] = u + b4[o];
            }
            int co = cp >> 2;
            int r1 = (cp >> 1) & 1;
            // o = cp..cp+1 -> (co, r1, r2=0/1); o = cp+64.. -> (co+16, r1, r2=0/1)
            float2* p0 = (float2*)(ob + (((size_t)co * 512) + (2 * gy + r1)) * 512 + 2 * gx);
            float2* p1 = (float2*)(ob + (((size_t)(co + 16) * 512) + (2 * gy + r1)) * 512 + 2 * gx);
            *p0 = make_float2(v[0], v[1]);
            *p1 = make_float2(v[2], v[3]);
        }
    }
}

// ---------------------------------------------------------------------------
extern "C" void kernel_launch(void* const* d_in, const int* in_sizes, int n_in,
                              void* d_out, int out_size, void* d_ws, size_t ws_size,
                              hipStream_t stream) {
    const float* x    = (const float*)d_in[0];
    const float* w1   = (const float*)d_in[1];
    const float* w2   = (const float*)d_in[2];
    const float* b_in = (const float*)d_in[3];
    // d_in[4]=b1, d_in[5]=s1, d_in[6]=b2 are dead code in the reference
    const float* b2_  = (const float*)d_in[7];
    const float* b3   = (const float*)d_in[8];
    const float* s2   = (const float*)d_in[9];
    const float* b4   = (const float*)d_in[10];
    float* out = (float*)d_out;

    char* ws = (char*)d_ws;
    u64*   w1b   = (u64*)(ws + 0);               // 64*9*8   = 4608
    u64*   w2b   = (u64*)(ws + 4608);            // 128*9*8  = 9216
    float* a1    = (float*)(ws + 13824);         // 256
    float* a2    = (float*)(ws + 14080);         // 512
    u64*   bits2 = (u64*)(ws + 16384);           // 8*65536*8 = 4194304
    __hip_bfloat16* xres = (__hip_bfloat16*)(ws + 16384 + 4194304);  // 8*64*65536*2 = 67108864

    prep_kernel<<<192, 64, 0, stream>>>(w1, w2, w1b, a1, w2b, a2);

    dim3 grid(IMG_W / 32, IMG_H / 32, 8);
    convbin1_kernel<<<grid, 256, 0, stream>>>(x, b_in, b2_, w1b, a1, xres, bits2);
    convbin2_kernel<<<grid, 256, 0, stream>>>(xres, bits2, w2b, a2, b3, s2, b4, out);
}

// Round 2
// 339.505 us; speedup vs baseline: 1.1937x; 1.1937x over previous
//
#include <hip/hip_runtime.h>
#include <hip/hip_bf16.h>

typedef unsigned long long u64;
typedef unsigned short ushort8 __attribute__((ext_vector_type(8)));

#define IMG_H 256
#define IMG_W 256
#define CIN   64
#define HW    (IMG_H * IMG_W)   // 65536
#define TS    16                // tile size (16x16, 1 px/thread, 256 threads)

static __device__ __forceinline__ float bf16bits_to_f32(unsigned short h) {
    union { unsigned int u; float f; } c;
    c.u = ((unsigned int)h) << 16;
    return c.f;
}

// ---------------------------------------------------------------------------
// Kernel P: pack weight sign bits + per-out-channel alpha = mean(|w|).
// One wave (64 lanes) per output channel; lane i <-> input channel i.
// ---------------------------------------------------------------------------
__global__ void prep_kernel(const float* __restrict__ w1,
                            const float* __restrict__ w2,
                            u64* __restrict__ w1b, float* __restrict__ a1,
                            u64* __restrict__ w2b, float* __restrict__ a2) {
    int blk = blockIdx.x;
    int lane = threadIdx.x;  // 0..63
    const float* w;
    u64* wb;
    float* al;
    if (blk < 64) { w = w1 + (size_t)blk * 576;        wb = w1b + blk * 9;        al = a1 + blk; }
    else          { w = w2 + (size_t)(blk - 64) * 576; wb = w2b + (blk - 64) * 9; al = a2 + (blk - 64); }

    const float* wi = w + lane * 9;
    float s = 0.f;
    u64 bits[9];
#pragma unroll
    for (int t = 0; t < 9; ++t) {
        float v = wi[t];
        s += fabsf(v);
        bits[t] = __ballot(v > 0.f);
    }
#pragma unroll
    for (int m = 32; m >= 1; m >>= 1) s += __shfl_xor(s, m);
    if (lane == 0) {
        *al = s * (1.f / 576.f);
#pragma unroll
        for (int t = 0; t < 9; ++t) wb[t] = bits[t];
    }
}

// ---------------------------------------------------------------------------
// Kernel A: conv1 (binary popcount) + residual.
//   xres stored CHANNEL-LAST bf16: xres[(n*HW + y*W + x)*64 + c]
//   bits2[n*HW + y*W + x] = packed sign(xres + b2_) bits
// ---------------------------------------------------------------------------
__global__ __launch_bounds__(256)
void convbin1_kernel(const float* __restrict__ x,
                     const float* __restrict__ b_in,
                     const float* __restrict__ b2_,
                     const u64* __restrict__ wbits,
                     const float* __restrict__ alpha1,
                     __hip_bfloat16* __restrict__ xres,
                     u64* __restrict__ bits2) {
    __shared__ u64 lb[18 * 18];
    const int n = blockIdx.z;
    const int ty0 = blockIdx.y * TS;
    const int tx0 = blockIdx.x * TS;
    const float* xn = x + (size_t)n * CIN * HW;

    // phase 1: pack sign(x + b_in) for tile + 1-halo
    for (int idx = threadIdx.x; idx < 18 * 18; idx += 256) {
        int ly = idx / 18, lx = idx % 18;
        int gy = ty0 + ly - 1, gx = tx0 + lx - 1;
        u64 wrd = 0;
        if (gy >= 0 && gy < IMG_H && gx >= 0 && gx < IMG_W) {
            const float* p = xn + gy * IMG_W + gx;
#pragma unroll 16
            for (int c = 0; c < 64; ++c) {
                float v = p[(size_t)c * HW] + b_in[c];
                wrd |= (u64)(v > 0.f) << c;
            }
        }
        lb[idx] = wrd;
    }
    __syncthreads();

    const int lx = threadIdx.x & (TS - 1);
    const int py = threadIdx.x >> 4;   // 0..15
    const int gy = ty0 + py;
    const int gx = tx0 + lx;

    u64 xb9[9];
    int invmask = 0, nv = 0;
#pragma unroll
    for (int t = 0; t < 9; ++t) {
        int dy = t / 3 - 1, dx = t % 3 - 1;
        int yy = gy + dy, xx = gx + dx;
        bool valid = (yy >= 0) & (yy < IMG_H) & (xx >= 0) & (xx < IMG_W);
        xb9[t] = lb[(py + 1 + dy) * 18 + (lx + 1 + dx)];
        invmask |= (valid ? 0 : 1) << t;
        nv += valid ? 1 : 0;
    }

    const float* xp = xn + gy * IMG_W + gx;
    __hip_bfloat16* rp = xres + ((size_t)n * HW + gy * IMG_W + gx) * 64;
    u64 w2word = 0;

#pragma unroll 1
    for (int oc = 0; oc < 8; ++oc) {
        ushort8 pk;
#pragma unroll
        for (int j = 0; j < 8; ++j) {
            int o = oc * 8 + j;
            const u64* wo = wbits + o * 9;
            int D = 0;
#pragma unroll
            for (int t = 0; t < 9; ++t) D += __popcll(xb9[t] ^ wo[t]);
            int S = 64 * nv - 2 * D;
            if (invmask) {
                int Dc = 0;
#pragma unroll
                for (int t = 0; t < 9; ++t)
                    if ((invmask >> t) & 1) Dc += __popcll(wo[t]);
                S += 2 * Dc;
            }
            float r = alpha1[o] * (float)S + xp[(size_t)o * HW];
            __hip_bfloat16 hb = __float2bfloat16(r);
            pk[j] = *(unsigned short*)&hb;
            w2word |= (u64)((r + b2_[o]) > 0.f) << o;
        }
        *reinterpret_cast<ushort8*>(rp + oc * 8) = pk;
    }
    bits2[(size_t)n * HW + gy * IMG_W + gx] = w2word;
}

// ---------------------------------------------------------------------------
// Kernel B: conv2 (binary popcount) + shortcut cat(xres,xres) + b3 + PReLU(s2)
//           + b4 + fused pixel_shuffle(2).
// out[n, co, 2y+r1, 2x+r2], o = co*4 + r1*2 + r2  (o in [0,128))
// ---------------------------------------------------------------------------
__global__ __launch_bounds__(256)
void convbin2_kernel(const __hip_bfloat16* __restrict__ xres,
                     const u64* __restrict__ bits2,
                     const u64* __restrict__ wbits,
                     const float* __restrict__ alpha2,
                     const float* __restrict__ b3,
                     const float* __restrict__ s2,
                     const float* __restrict__ b4,
                     float* __restrict__ out) {
    __shared__ u64 lb[18 * 18];
    const int n = blockIdx.z;
    const int ty0 = blockIdx.y * TS;
    const int tx0 = blockIdx.x * TS;
    const u64* bn = bits2 + (size_t)n * HW;

    for (int idx = threadIdx.x; idx < 18 * 18; idx += 256) {
        int ly = idx / 18, lx = idx % 18;
        int gy = ty0 + ly - 1, gx = tx0 + lx - 1;
        u64 wrd = 0;
        if (gy >= 0 && gy < IMG_H && gx >= 0 && gx < IMG_W)
            wrd = bn[gy * IMG_W + gx];
        lb[idx] = wrd;
    }
    __syncthreads();

    const int lx = threadIdx.x & (TS - 1);
    const int py = threadIdx.x >> 4;
    const int gy = ty0 + py;
    const int gx = tx0 + lx;

    u64 xb9[9];
    int invmask = 0, nv = 0;
#pragma unroll
    for (int t = 0; t < 9; ++t) {
        int dy = t / 3 - 1, dx = t % 3 - 1;
        int yy = gy + dy, xx = gx + dx;
        bool valid = (yy >= 0) & (yy < IMG_H) & (xx >= 0) & (xx < IMG_W);
        xb9[t] = lb[(py + 1 + dy) * 18 + (lx + 1 + dx)];
        invmask |= (valid ? 0 : 1) << t;
        nv += valid ? 1 : 0;
    }

    // load this pixel's 64 residual channels (channel-last, 128B contiguous)
    const ushort8* xrp = reinterpret_cast<const ushort8*>(
        xres + ((size_t)n * HW + gy * IMG_W + gx) * 64);
    float* ob = out + (size_t)n * 32 * 512 * 512;

#pragma unroll 1
    for (int c8 = 0; c8 < 8; ++c8) {
        ushort8 xr = xrp[c8];
        float vlo[8], vhi[8];
#pragma unroll
        for (int j = 0; j < 8; ++j) {
            int o = c8 * 8 + j;
            float xrv = bf16bits_to_f32(xr[j]);
            // low channel o
            {
                const u64* wo = wbits + o * 9;
                int D = 0;
#pragma unroll
                for (int t = 0; t < 9; ++t) D += __popcll(xb9[t] ^ wo[t]);
                int S = 64 * nv - 2 * D;
                if (invmask) {
                    int Dc = 0;
#pragma unroll
                    for (int t = 0; t < 9; ++t)
                        if ((invmask >> t) & 1) Dc += __popcll(wo[t]);
                    S += 2 * Dc;
                }
                float u = 1.25f * alpha2[o] * (float)S + xrv + b3[o];
                u = (u >= 0.f) ? u : s2[o] * u;
                vlo[j] = u + b4[o];
            }
            // high channel o + 64
            {
                int o2 = o + 64;
                const u64* wo = wbits + o2 * 9;
                int D = 0;
#pragma unroll
                for (int t = 0; t < 9; ++t) D += __popcll(xb9[t] ^ wo[t]);
                int S = 64 * nv - 2 * D;
                if (invmask) {
                    int Dc = 0;
#pragma unroll
                    for (int t = 0; t < 9; ++t)
                        if ((invmask >> t) & 1) Dc += __popcll(wo[t]);
                    S += 2 * Dc;
                }
                float u = 1.25f * alpha2[o2] * (float)S + xrv + b3[o2];
                u = (u >= 0.f) ? u : s2[o2] * u;
                vhi[j] = u + b4[o2];
            }
        }
        // paired stores with fused pixel shuffle: channels (o,o+1), even o,
        // share (co, r1) and write adjacent columns 2gx, 2gx+1.
#pragma unroll
        for (int jj = 0; jj < 8; jj += 2) {
            int o = c8 * 8 + jj;
            int co = o >> 2;
            int r1 = (o >> 1) & 1;
            *(float2*)(ob + (((size_t)co * 512) + (2 * gy + r1)) * 512 + 2 * gx) =
                make_float2(vlo[jj], vlo[jj + 1]);
            *(float2*)(ob + (((size_t)(co + 16) * 512) + (2 * gy + r1)) * 512 + 2 * gx) =
                make_float2(vhi[jj], vhi[jj + 1]);
        }
    }
}

// ---------------------------------------------------------------------------
extern "C" void kernel_launch(void* const* d_in, const int* in_sizes, int n_in,
                              void* d_out, int out_size, void* d_ws, size_t ws_size,
                              hipStream_t stream) {
    const float* x    = (const float*)d_in[0];
    const float* w1   = (const float*)d_in[1];
    const float* w2   = (const float*)d_in[2];
    const float* b_in = (const float*)d_in[3];
    // d_in[4]=b1, d_in[5]=s1, d_in[6]=b2 are dead code in the reference
    const float* b2_  = (const float*)d_in[7];
    const float* b3   = (const float*)d_in[8];
    const float* s2   = (const float*)d_in[9];
    const float* b4   = (const float*)d_in[10];
    float* out = (float*)d_out;

    char* ws = (char*)d_ws;
    u64*   w1b   = (u64*)(ws + 0);               // 64*9*8   = 4608
    u64*   w2b   = (u64*)(ws + 4608);            // 128*9*8  = 9216
    float* a1    = (float*)(ws + 13824);         // 256
    float* a2    = (float*)(ws + 14080);         // 512
    u64*   bits2 = (u64*)(ws + 16384);           // 8*65536*8 = 4194304
    __hip_bfloat16* xres = (__hip_bfloat16*)(ws + 16384 + 4194304);  // 67108864 (channel-last)

    prep_kernel<<<192, 64, 0, stream>>>(w1, w2, w1b, a1, w2b, a2);

    dim3 grid(IMG_W / TS, IMG_H / TS, 8);
    convbin1_kernel<<<grid, 256, 0, stream>>>(x, b_in, b2_, w1b, a1, xres, bits2);
    convbin2_kernel<<<grid, 256, 0, stream>>>(xres, bits2, w2b, a2, b3, s2, b4, out);
}

// Round 3
// 241.554 us; speedup vs baseline: 1.6777x; 1.4055x over previous
//
#include <hip/hip_runtime.h>
#include <hip/hip_bf16.h>

typedef unsigned long long u64;
typedef unsigned short ushort8 __attribute__((ext_vector_type(8)));

#define IMG_H 256
#define IMG_W 256
#define CIN   64
#define HW    (IMG_H * IMG_W)   // 65536
#define NPIX  (8 * HW)          // 524288

static __device__ __forceinline__ float bf16bits_to_f32(unsigned short h) {
    union { unsigned int u; float f; } c;
    c.u = ((unsigned int)h) << 16;
    return c.f;
}

// ---------------------------------------------------------------------------
// Kernel P: pack weight sign bits + per-out-channel alpha = mean(|w|).
// ---------------------------------------------------------------------------
__global__ void prep_kernel(const float* __restrict__ w1,
                            const float* __restrict__ w2,
                            u64* __restrict__ w1b, float* __restrict__ a1,
                            u64* __restrict__ w2b, float* __restrict__ a2) {
    int blk = blockIdx.x;
    int lane = threadIdx.x;  // 0..63
    const float* w;
    u64* wb;
    float* al;
    if (blk < 64) { w = w1 + (size_t)blk * 576;        wb = w1b + blk * 9;        al = a1 + blk; }
    else          { w = w2 + (size_t)(blk - 64) * 576; wb = w2b + (blk - 64) * 9; al = a2 + (blk - 64); }

    const float* wi = w + lane * 9;
    float s = 0.f;
    u64 bits[9];
#pragma unroll
    for (int t = 0; t < 9; ++t) {
        float v = wi[t];
        s += fabsf(v);
        bits[t] = __ballot(v > 0.f);
    }
#pragma unroll
    for (int m = 32; m >= 1; m >>= 1) s += __shfl_xor(s, m);
    if (lane == 0) {
        *al = s * (1.f / 576.f);
#pragma unroll
        for (int t = 0; t < 9; ++t) wb[t] = bits[t];
    }
}

// ---------------------------------------------------------------------------
// Kernel 1: pack sign(x + b_in) into a global bit-plane. Pure stream.
// ---------------------------------------------------------------------------
__global__ __launch_bounds__(256)
void pack_kernel(const float* __restrict__ x,
                 const float* __restrict__ b_in,
                 u64* __restrict__ bits1) {
    int i = blockIdx.x * 256 + threadIdx.x;   // pixel id over [0, NPIX)
    int n = i >> 16, p = i & 65535;
    const float* xp = x + (size_t)n * CIN * HW + p;
    u64 w = 0;
#pragma unroll
    for (int c = 0; c < 64; ++c)
        w |= (u64)((xp[(size_t)c * HW] + b_in[c]) > 0.f) << c;
    bits1[i] = w;
}

// ---------------------------------------------------------------------------
// Kernel 2: conv1 (binary popcount from bits1) + residual.
//   xres stored channel-group-blocked bf16: plane (n*8+g), element [p][8]
//   bits2[i] = packed sign(xres + b2_) bits
// ---------------------------------------------------------------------------
__global__ __launch_bounds__(256)
void conv1_kernel(const float* __restrict__ x,
                  const float* __restrict__ b2_,
                  const u64* __restrict__ bits1,
                  const u64* __restrict__ wbits,
                  const float* __restrict__ alpha1,
                  ushort8* __restrict__ xres,
                  u64* __restrict__ bits2) {
    int i = blockIdx.x * 256 + threadIdx.x;
    int n = i >> 16, p = i & 65535;
    int y = p >> 8, xc = p & 255;

    u64 xb[9];
    int invmask = 0, nv = 0;
#pragma unroll
    for (int t = 0; t < 9; ++t) {
        int dy = t / 3 - 1, dx = t % 3 - 1;
        bool v = ((unsigned)(y + dy) < (unsigned)IMG_H) &
                 ((unsigned)(xc + dx) < (unsigned)IMG_W);
        xb[t] = v ? bits1[i + dy * IMG_W + dx] : 0ull;
        invmask |= (v ? 0 : 1) << t;
        nv += v ? 1 : 0;
    }

    const float* xp = x + (size_t)n * CIN * HW + p;
    u64 w2 = 0;

#pragma unroll 1
    for (int g = 0; g < 8; ++g) {
        ushort8 pk;
#pragma unroll
        for (int j = 0; j < 8; ++j) {
            int o = g * 8 + j;
            const u64* wo = wbits + o * 9;
            int D = 0;
#pragma unroll
            for (int t = 0; t < 9; ++t) D += __popcll(xb[t] ^ wo[t]);
            int S = 64 * nv - 2 * D;
            if (invmask) {
                int Dc = 0;
#pragma unroll
                for (int t = 0; t < 9; ++t)
                    if ((invmask >> t) & 1) Dc += __popcll(wo[t]);
                S += 2 * Dc;
            }
            float r = alpha1[o] * (float)S + xp[(size_t)o * HW];
            __hip_bfloat16 hb = __float2bfloat16(r);
            pk[j] = *(unsigned short*)&hb;
            w2 |= (u64)((r + b2_[o]) > 0.f) << o;
        }
        xres[(size_t)(n * 8 + g) * HW + p] = pk;   // 16B/lane, lanes contiguous
    }
    bits2[i] = w2;
}

// ---------------------------------------------------------------------------
// Kernel 3: conv2 (binary popcount from bits2) + shortcut cat(xres,xres)
//           + b3 + PReLU(s2) + b4 + fused pixel_shuffle(2).
// ---------------------------------------------------------------------------
__global__ __launch_bounds__(256)
void conv2_kernel(const ushort8* __restrict__ xres,
                  const u64* __restrict__ bits2,
                  const u64* __restrict__ wbits,
                  const float* __restrict__ alpha2,
                  const float* __restrict__ b3,
                  const float* __restrict__ s2,
                  const float* __restrict__ b4,
                  float* __restrict__ out) {
    int i = blockIdx.x * 256 + threadIdx.x;
    int n = i >> 16, p = i & 65535;
    int y = p >> 8, xc = p & 255;

    u64 xb[9];
    int invmask = 0, nv = 0;
#pragma unroll
    for (int t = 0; t < 9; ++t) {
        int dy = t / 3 - 1, dx = t % 3 - 1;
        bool v = ((unsigned)(y + dy) < (unsigned)IMG_H) &
                 ((unsigned)(xc + dx) < (unsigned)IMG_W);
        xb[t] = v ? bits2[i + dy * IMG_W + dx] : 0ull;
        invmask |= (v ? 0 : 1) << t;
        nv += v ? 1 : 0;
    }

    float* ob = out + (size_t)n * 32 * 512 * 512;
    const int Y = 2 * y, X = 2 * xc;

#pragma unroll 1
    for (int g = 0; g < 8; ++g) {
        ushort8 xr = xres[(size_t)(n * 8 + g) * HW + p];
        float vlo[8], vhi[8];
#pragma unroll
        for (int j = 0; j < 8; ++j) {
            int o = g * 8 + j;
            float xrv = bf16bits_to_f32(xr[j]);
            {
                const u64* wo = wbits + o * 9;
                int D = 0;
#pragma unroll
                for (int t = 0; t < 9; ++t) D += __popcll(xb[t] ^ wo[t]);
                int S = 64 * nv - 2 * D;
                if (invmask) {
                    int Dc = 0;
#pragma unroll
                    for (int t = 0; t < 9; ++t)
                        if ((invmask >> t) & 1) Dc += __popcll(wo[t]);
                    S += 2 * Dc;
                }
                float u = 1.25f * alpha2[o] * (float)S + xrv + b3[o];
                u = (u >= 0.f) ? u : s2[o] * u;
                vlo[j] = u + b4[o];
            }
            {
                int o2 = o + 64;
                const u64* wo = wbits + o2 * 9;
                int D = 0;
#pragma unroll
                for (int t = 0; t < 9; ++t) D += __popcll(xb[t] ^ wo[t]);
                int S = 64 * nv - 2 * D;
                if (invmask) {
                    int Dc = 0;
#pragma unroll
                    for (int t = 0; t < 9; ++t)
                        if ((invmask >> t) & 1) Dc += __popcll(wo[t]);
                    S += 2 * Dc;
                }
                float u = 1.25f * alpha2[o2] * (float)S + xrv + b3[o2];
                u = (u >= 0.f) ? u : s2[o2] * u;
                vhi[j] = u + b4[o2];
            }
        }
        // fused pixel shuffle: o = co*4 + r1*2 + r2; pairs (o,o+1) share row
#pragma unroll
        for (int jj = 0; jj < 8; jj += 2) {
            int o = g * 8 + jj;
            int co = o >> 2;
            int r1 = (o >> 1) & 1;
            *(float2*)(ob + ((size_t)co * 512 + Y + r1) * 512 + X) =
                make_float2(vlo[jj], vlo[jj + 1]);
            *(float2*)(ob + ((size_t)(co + 16) * 512 + Y + r1) * 512 + X) =
                make_float2(vhi[jj], vhi[jj + 1]);
        }
    }
}

// ---------------------------------------------------------------------------
extern "C" void kernel_launch(void* const* d_in, const int* in_sizes, int n_in,
                              void* d_out, int out_size, void* d_ws, size_t ws_size,
                              hipStream_t stream) {
    const float* x    = (const float*)d_in[0];
    const float* w1   = (const float*)d_in[1];
    const float* w2   = (const float*)d_in[2];
    const float* b_in = (const float*)d_in[3];
    // d_in[4]=b1, d_in[5]=s1, d_in[6]=b2 are dead code in the reference
    const float* b2_  = (const float*)d_in[7];
    const float* b3   = (const float*)d_in[8];
    const float* s2   = (const float*)d_in[9];
    const float* b4   = (const float*)d_in[10];
    float* out = (float*)d_out;

    char* ws = (char*)d_ws;
    u64*   w1b   = (u64*)(ws + 0);                    // 4608 B
    u64*   w2b   = (u64*)(ws + 4608);                 // 9216 B
    float* a1    = (float*)(ws + 13824);              // 256 B
    float* a2    = (float*)(ws + 14080);              // 512 B
    u64*   bits1 = (u64*)(ws + 16384);                // 4 MiB
    u64*   bits2 = (u64*)(ws + 16384 + 4194304);      // 4 MiB
    ushort8* xres = (ushort8*)(ws + 16384 + 2 * 4194304);  // 64 MiB (blocked bf16)

    prep_kernel<<<192, 64, 0, stream>>>(w1, w2, w1b, a1, w2b, a2);

    const int nblk = NPIX / 256;  // 2048
    pack_kernel <<<nblk, 256, 0, stream>>>(x, b_in, bits1);
    conv1_kernel<<<nblk, 256, 0, stream>>>(x, b2_, bits1, w1b, a1, xres, bits2);
    conv2_kernel<<<nblk, 256, 0, stream>>>(xres, bits2, w2b, a2, b3, s2, b4, out);
}